// Round 6
// baseline (202.431 us; speedup 1.0000x reference)
//
#include <hip/hip_runtime.h>

// Mamba block forward. Round 6: polynomial sin/cos in scan inner loop
// (3 trans -> 1 trans per step), unroll 8 for load ILP.
constexpr int B  = 2, L = 1024, DM = 512, DI = 1024, NST = 16, PW = 97;
constexpr int ML = B * L;                   // 2048 rows
constexpr int NCHUNK = 32, CL = L / NCHUNK; // 32 chunks x 32 steps
constexpr int NLANES = B * DI * NST;        // 32768 scan lanes

#define DEV_INLINE __device__ __forceinline__

typedef __attribute__((ext_vector_type(8))) short bf16x8;   // 8 bf16 (4 VGPRs)
typedef __attribute__((ext_vector_type(4))) float f32x4;    // 4 fp32 acc

DEV_INLINE float sigmoidf_(float x) { return 1.f / (1.f + __expf(-x)); }
DEV_INLINE unsigned short f2bf(float f) {
  unsigned int u = __float_as_uint(f);
  return (unsigned short)((u + 0x7FFFu + ((u >> 16) & 1u)) >> 16);  // RNE
}

#if __has_builtin(__builtin_amdgcn_exp2f)
#define EXP2F(x) __builtin_amdgcn_exp2f(x)
#else
#define EXP2F(x) exp2f(x)
#endif
#if __has_builtin(__builtin_amdgcn_sinf)
#define SINR(x) __builtin_amdgcn_sinf(x)   // sin(2*pi*x), x in revolutions
#define COSR(x) __builtin_amdgcn_cosf(x)
#else
#define SINR(x) __sinf((x) * 6.2831853f)
#define COSR(x) __cosf((x) * 6.2831853f)
#endif

// Taylor sin/cos (radians), valid |th| <~ 2 with <5e-5 error. Shares t2.
DEV_INLINE void sincos_poly(float th, float& s, float& c) {
  float t2 = th * th;
  float u = fmaf(t2, 2.7557319e-6f, -1.9841270e-4f);
  u = fmaf(t2, u, 8.3333333e-3f);
  u = fmaf(t2, u, -0.16666667f);
  u = fmaf(t2, u, 1.f);
  s = th * u;
  float v = fmaf(t2, 2.4801587e-5f, -1.3888889e-3f);
  v = fmaf(t2, v, 4.1666667e-2f);
  v = fmaf(t2, v, -0.5f);
  c = fmaf(t2, v, 1.f);
}

// ---------------------------------------------------------------------------
// f32 -> bf16 convert, 3 segments in one launch (x, in_proj_w, out_proj_w)
// ---------------------------------------------------------------------------
__global__ __launch_bounds__(256) void cvt3_k(
    const float* __restrict__ i0, unsigned short* __restrict__ o0, int n0,
    const float* __restrict__ i1, unsigned short* __restrict__ o1, int n1,
    const float* __restrict__ i2, unsigned short* __restrict__ o2, int n2) {
  int i = blockIdx.x * 256 + threadIdx.x;   // in float4 units
  const float* in; unsigned short* out; int off;
  if (i < n0)              { in = i0; out = o0; off = i; }
  else if (i < n0 + n1)    { in = i1; out = o1; off = i - n0; }
  else if (i < n0 + n1 + n2) { in = i2; out = o2; off = i - n0 - n1; }
  else return;
  float4 v = ((const float4*)in)[off];
  ((ushort4*)out)[off] = make_ushort4(f2bf(v.x), f2bf(v.y), f2bf(v.z), f2bf(v.w));
}

// ---------------------------------------------------------------------------
// bf16 MFMA GEMM, 64x64 tile, BK=64, 4 waves, XOR-swizzled LDS.
// ---------------------------------------------------------------------------
DEV_INLINE int swz(int row, int kb) { return (row << 7) + (kb ^ ((row & 7) << 4)); }

__global__ __launch_bounds__(256) void gemm_bf16_64(
    const short* __restrict__ A, const short* __restrict__ W,
    float* __restrict__ C, int M, int N, int K) {
  __shared__ char ldsb[16384];               // A [0,8K), W [8K,16K)
  const int tid = threadIdx.x;
  const int lane = tid & 63, wv = tid >> 6;
  const int bm = blockIdx.y * 64, bn = blockIdx.x * 64;

  f32x4 acc[4];
#pragma unroll
  for (int nb = 0; nb < 4; ++nb) acc[nb] = (f32x4){0.f, 0.f, 0.f, 0.f};

  for (int k0 = 0; k0 < K; k0 += 64) {
#pragma unroll
    for (int i = 0; i < 2; ++i) {
      int off = i * 4096 + tid * 16;
      int row = off >> 7, kb = off & 127;
      bf16x8 va = *(const bf16x8*)(A + (size_t)(bm + row) * K + k0 + (kb >> 1));
      bf16x8 vw = *(const bf16x8*)(W + (size_t)(bn + row) * K + k0 + (kb >> 1));
      *(bf16x8*)(ldsb + swz(row, kb)) = va;
      *(bf16x8*)(ldsb + 8192 + swz(row, kb)) = vw;
    }
    __syncthreads();
#pragma unroll
    for (int ks = 0; ks < 2; ++ks) {
      const int kb = ks * 64 + ((lane >> 4) << 4);
      bf16x8 af = *(const bf16x8*)(ldsb + swz(wv * 16 + (lane & 15), kb));
#pragma unroll
      for (int nb = 0; nb < 4; ++nb) {
        bf16x8 bfv = *(const bf16x8*)(ldsb + 8192 + swz(nb * 16 + (lane & 15), kb));
        acc[nb] = __builtin_amdgcn_mfma_f32_16x16x32_bf16(af, bfv, acc[nb], 0, 0, 0);
      }
    }
    __syncthreads();
  }
#pragma unroll
  for (int nb = 0; nb < 4; ++nb) {
    int col = bn + nb * 16 + (lane & 15);
    int row0 = bm + wv * 16 + ((lane >> 4) << 2);
#pragma unroll
    for (int j = 0; j < 4; ++j)
      C[(size_t)(row0 + j) * N + col] = acc[nb][j];
  }
}

// ---------------------------------------------------------------------------
// causal depthwise conv (K=3) + bias + SiLU -> xc; silu(z) -> sz. float4.
// ---------------------------------------------------------------------------
__global__ __launch_bounds__(256) void conv_silu_k(
    const float* __restrict__ xz, const float* __restrict__ cw,
    const float* __restrict__ cb, float* __restrict__ xc, float* __restrict__ sz) {
  int idx = blockIdx.x * 256 + threadIdx.x;   // float4 unit: (m, d4)
  int m = idx >> 8, d4 = (idx & 255) * 4;
  int t = m & (L - 1);
  const float* base = xz + (size_t)m * (2 * DI);
  float4 r2 = *(const float4*)(base + d4);
  float4 r1 = (t >= 1) ? *(const float4*)(base - 2 * DI + d4) : make_float4(0, 0, 0, 0);
  float4 r0 = (t >= 2) ? *(const float4*)(base - 4 * DI + d4) : make_float4(0, 0, 0, 0);
  float4 zv = *(const float4*)(base + DI + d4);
  float wv[12];
  *(float4*)(wv + 0) = *(const float4*)(cw + d4 * 3 + 0);
  *(float4*)(wv + 4) = *(const float4*)(cw + d4 * 3 + 4);
  *(float4*)(wv + 8) = *(const float4*)(cw + d4 * 3 + 8);
  float4 bv = *(const float4*)(cb + d4);
  float rin0[4] = {r0.x, r0.y, r0.z, r0.w};
  float rin1[4] = {r1.x, r1.y, r1.z, r1.w};
  float rin2[4] = {r2.x, r2.y, r2.z, r2.w};
  float bb[4] = {bv.x, bv.y, bv.z, bv.w};
  float zz[4] = {zv.x, zv.y, zv.z, zv.w};
  float xo[4], zo[4];
#pragma unroll
  for (int j = 0; j < 4; ++j) {
    float v = bb[j];
    v = fmaf(rin0[j], wv[3 * j + 0], v);
    v = fmaf(rin1[j], wv[3 * j + 1], v);
    v = fmaf(rin2[j], wv[3 * j + 2], v);
    xo[j] = v * sigmoidf_(v);
    zo[j] = zz[j] * sigmoidf_(zz[j]);
  }
  *(float4*)(xc + (size_t)idx * 4) = make_float4(xo[0], xo[1], xo[2], xo[3]);
  *(float4*)(sz + (size_t)idx * 4) = make_float4(zo[0], zo[1], zo[2], zo[3]);
}

// ---------------------------------------------------------------------------
// x_proj: (ML,1024) x (97,1024)^T, K split 4 ways, LDS combine, scattered.
// ---------------------------------------------------------------------------
__global__ __launch_bounds__(512) void proj_k(
    const float* __restrict__ xc, const float* __restrict__ xw,
    float* __restrict__ dtp, float* __restrict__ bccf, float* __restrict__ lamv) {
  __shared__ float xs[4][DI];
  __shared__ float pt[3][4][128];
  const int tid = threadIdx.x;
  const int m0 = blockIdx.x * 4;
  const int nn = tid & 127, qq = tid >> 7;
  for (int i = tid; i < 4 * DI; i += 512)
    xs[i >> 10][i & 1023] = xc[(size_t)m0 * DI + i];
  __syncthreads();
  float s0 = 0.f, s1 = 0.f, s2 = 0.f, s3 = 0.f;
  if (nn < PW) {
    const float* wr = xw + (size_t)nn * DI + qq * 256;
    const int kb = qq * 256;
#pragma unroll 4
    for (int k = 0; k < 256; k += 4) {
      float4 w4 = *(const float4*)(wr + k);
      s0 = fmaf(xs[0][kb + k], w4.x, s0); s0 = fmaf(xs[0][kb + k + 1], w4.y, s0);
      s0 = fmaf(xs[0][kb + k + 2], w4.z, s0); s0 = fmaf(xs[0][kb + k + 3], w4.w, s0);
      s1 = fmaf(xs[1][kb + k], w4.x, s1); s1 = fmaf(xs[1][kb + k + 1], w4.y, s1);
      s1 = fmaf(xs[1][kb + k + 2], w4.z, s1); s1 = fmaf(xs[1][kb + k + 3], w4.w, s1);
      s2 = fmaf(xs[2][kb + k], w4.x, s2); s2 = fmaf(xs[2][kb + k + 1], w4.y, s2);
      s2 = fmaf(xs[2][kb + k + 2], w4.z, s2); s2 = fmaf(xs[2][kb + k + 3], w4.w, s2);
      s3 = fmaf(xs[3][kb + k], w4.x, s3); s3 = fmaf(xs[3][kb + k + 1], w4.y, s3);
      s3 = fmaf(xs[3][kb + k + 2], w4.z, s3); s3 = fmaf(xs[3][kb + k + 3], w4.w, s3);
    }
    if (qq > 0) {
      pt[qq - 1][0][nn] = s0; pt[qq - 1][1][nn] = s1;
      pt[qq - 1][2][nn] = s2; pt[qq - 1][3][nn] = s3;
    }
  }
  __syncthreads();
  if (qq == 0 && nn < PW) {
    s0 += pt[0][0][nn] + pt[1][0][nn] + pt[2][0][nn];
    s1 += pt[0][1][nn] + pt[1][1][nn] + pt[2][1][nn];
    s2 += pt[0][2][nn] + pt[1][2][nn] + pt[2][2][nn];
    s3 += pt[0][3][nn] + pt[1][3][nn] + pt[2][3][nn];
    float sv[4] = {s0, s1, s2, s3};
#pragma unroll
    for (int r = 0; r < 4; ++r) {
      int m = m0 + r;
      float s = sv[r];
      if (nn < 32)        dtp[m * 32 + nn] = s;
      else if (nn < 48)   bccf[(m * 16 + nn - 32) * 4 + 0] = s;
      else if (nn < 64)   bccf[(m * 16 + nn - 48) * 4 + 1] = s;
      else if (nn < 80)   bccf[(m * 16 + nn - 64) * 4 + 2] = s;
      else if (nn < 96)   bccf[(m * 16 + nn - 80) * 4 + 3] = s;
      else                lamv[m] = sigmoidf_(s);
    }
  }
}

// ---------------------------------------------------------------------------
// delta = softplus(dtp @ dt_w^T + dt_b); emit packed float4 {dlt, xt, bsc, g}
// ---------------------------------------------------------------------------
__global__ __launch_bounds__(256) void delta_k(
    const float* __restrict__ dtp, const float* __restrict__ dtw,
    const float* __restrict__ dtb, const float* __restrict__ xc,
    const float* __restrict__ lamv, float4* __restrict__ dxbg) {
  __shared__ float ws[256][33];
  __shared__ float ps[8][32];
  const int tid = threadIdx.x;
  const int d0 = blockIdx.x * 256;
  const int m0 = blockIdx.y * 8;
#pragma unroll
  for (int j = 0; j < 8; ++j) {
    int flat = tid * 4 + j * 1024;
    int r = flat >> 5, c = flat & 31;
    float4 v = *(const float4*)(dtw + (size_t)d0 * 32 + flat);
    ws[r][c] = v.x; ws[r][c + 1] = v.y; ws[r][c + 2] = v.z; ws[r][c + 3] = v.w;
  }
  { int i = tid >> 5, r = tid & 31;
    ps[i][r] = dtp[(size_t)(m0 + i) * 32 + r]; }
  __syncthreads();
  float s[8];
  float bias = dtb[d0 + tid];
#pragma unroll
  for (int i = 0; i < 8; ++i) s[i] = bias;
#pragma unroll
  for (int r = 0; r < 32; ++r) {
    float wv = ws[tid][r];
#pragma unroll
    for (int i = 0; i < 8; ++i) s[i] = fmaf(ps[i][r], wv, s[i]);
  }
#pragma unroll
  for (int i = 0; i < 8; ++i) {
    float x = s[i];
    float dlt = (x > 20.f) ? x : log1pf(__expf(x));
    int m = m0 + i;
    float xt = xc[(size_t)m * DI + d0 + tid];
    float lam = lamv[m];
    dxbg[(size_t)m * DI + d0 + tid] = make_float4(dlt, xt, (1.f - lam) * dlt, lam * dlt);
  }
}

// ---------------------------------------------------------------------------
// Chunked selective scan. lane = n (0..15); 16 (b,d) channels per block.
// h_t = alpha*(h_{t-1} + bsc*Bx_{t-1}) + g*Bx_t. Poly sin/cos in loop
// (theta = dlt*Ai < ~0.5 rad); HW sin/cos only in the once-per-chunk tail.
// ---------------------------------------------------------------------------
template <bool PASS_B>
__global__ __launch_bounds__(256) void scan_pass(
    const float4* __restrict__ dxbg, const float4* __restrict__ bcc,
    const float* __restrict__ sz,
    const float* __restrict__ A_log, const float* __restrict__ A_imag,
    const float* __restrict__ D_skip,
    float2* __restrict__ aggA, float2* __restrict__ aggU,
    unsigned short* __restrict__ ybuf) {
  const int tid = threadIdx.x;
  const int n = tid & 15;
  const int gch = blockIdx.x * 16 + (tid >> 4);
  const int c = blockIdx.y;
  const int b = gch >> 10, d = gch & 1023;
  const int lane = blockIdx.x * 256 + tid;
  const float Ar = -__expf(A_log[d * 16 + n]);
  const float Arl = Ar * 1.44269504f;                  // * log2(e)
  const float Ai = A_imag[d * 16 + n];                 // radians multiplier
  const int t0 = c * CL, mb = b * L;
  const unsigned ix0 = (unsigned)(mb + t0) * DI + d;

  float Bxpr = 0.f, Bxpi = 0.f;
  if (c > 0) {
    float xp = dxbg[ix0 - DI].y;
    float4 bp = bcc[(mb + t0 - 1) * 16 + n];
    Bxpr = bp.x * xp; Bxpi = bp.y * xp;
  }
  float hr = 0.f, hi = 0.f, S = 0.f, Dsk = 0.f;
  if (PASS_B) {
    if (c > 0) {
      float2 h0 = aggU[(c - 1) * NLANES + lane];  // prefix from combine
      hr = h0.x; hi = h0.y;
    }
    Dsk = D_skip[d];
  }

  const float4* qp = dxbg + ix0;
  const float4* pp = bcc + (size_t)(mb + t0) * 16 + n;
#pragma unroll 8
  for (int t = 0; t < CL; ++t) {
    float4 q = qp[(size_t)t * DI];      // {dlt, xt, bsc, g}
    float4 p = pp[(size_t)t * 16];      // {Br, Bi, Cr, Ci}
    float ear = EXP2F(q.x * Arl);
    float sn, cs;
    sincos_poly(q.x * Ai, sn, cs);
    float ar = ear * cs, ai = ear * sn;
    float Bxr = p.x * q.y, Bxi = p.y * q.y;
    float wr = fmaf(q.z, Bxpr, hr), wi = fmaf(q.z, Bxpi, hi);
    hr = fmaf(q.w, Bxr, fmaf(-ai, wi, ar * wr));
    hi = fmaf(q.w, Bxi, fmaf(ai, wr, ar * wi));
    Bxpr = Bxr; Bxpi = Bxi;
    if (!PASS_B) {
      S += q.x;
    } else {
      float yc = fmaf(hi, p.w, hr * p.z);  // Re(h * conj(C))
      yc += __shfl_xor(yc, 1);
      yc += __shfl_xor(yc, 2);
      yc += __shfl_xor(yc, 4);
      yc += __shfl_xor(yc, 8);
      if (n == 0) {
        unsigned ixm = ix0 + ((unsigned)t << 10);
        float y = fmaf(Dsk, q.y, yc);
        ybuf[ixm] = f2bf(y * sz[ixm]);
      }
    }
  }
  if (!PASS_B) {
    float earS = EXP2F(S * Arl);
    float rvS = S * Ai * 0.15915494f;     // revolutions for HW sin/cos
    float AaR = earS * COSR(rvS);
    float AaI = earS * SINR(rvS);
    int idx = c * NLANES + lane;
    aggA[idx] = make_float2(AaR, AaI);
    aggU[idx] = make_float2(hr, hi);
  }
}

// in-place prefix: after this, aggU[c] = chunk-(c+1) entry state
__global__ __launch_bounds__(256) void scan_combine_k(
    const float2* __restrict__ aggA, float2* __restrict__ aggU) {
  int gid = blockIdx.x * 256 + threadIdx.x;
  float hr = 0.f, hi = 0.f;
#pragma unroll
  for (int c = 0; c < NCHUNK - 1; ++c) {
    float2 a = aggA[c * NLANES + gid];
    float2 u = aggU[c * NLANES + gid];
    float nr = fmaf(a.x, hr, fmaf(-a.y, hi, u.x));
    float ni = fmaf(a.x, hi, fmaf(a.y, hr, u.y));
    hr = nr; hi = ni;
    aggU[c * NLANES + gid] = make_float2(hr, hi);
  }
}

extern "C" void kernel_launch(void* const* d_in, const int* in_sizes, int n_in,
                              void* d_out, int out_size, void* d_ws, size_t ws_size,
                              hipStream_t stream) {
  const float* x        = (const float*)d_in[0];
  const float* in_proj  = (const float*)d_in[1];
  const float* conv_w   = (const float*)d_in[2];
  const float* conv_b   = (const float*)d_in[3];
  const float* x_proj_w = (const float*)d_in[4];
  const float* dt_w     = (const float*)d_in[5];
  const float* dt_b     = (const float*)d_in[6];
  const float* A_log    = (const float*)d_in[7];
  const float* A_imag   = (const float*)d_in[8];
  const float* D_skip   = (const float*)d_in[9];
  const float* out_proj = (const float*)d_in[10];
  float* out = (float*)d_out;

  float* ws = (float*)d_ws;
  float*  xz    = ws; ws += (size_t)ML * 2 * DI;                 // 16.8 MB
  float*  xc    = ws; ws += (size_t)ML * DI;                     //  8.4 MB
  float*  sz    = ws; ws += (size_t)ML * DI;                     //  8.4 MB
  float4* dxbg  = (float4*)ws; ws += (size_t)(ML + 1) * DI * 4;  // 33.6 MB
  float*  dtp   = ws; ws += (size_t)ML * 32;
  float*  bccf  = ws; ws += (size_t)(ML + 1) * 16 * 4;
  float*  lamv  = ws; ws += ML;
  float2* aggA  = (float2*)ws; ws += (size_t)NCHUNK * NLANES * 2; // 8.4 MB
  float2* aggU  = (float2*)ws; ws += (size_t)NCHUNK * NLANES * 2; // 8.4 MB
  unsigned short* xb   = (unsigned short*)ws; ws += (size_t)ML * DM / 2;
  unsigned short* wb1  = (unsigned short*)ws; ws += (size_t)(2 * DI) * DM / 2;
  unsigned short* wb2  = (unsigned short*)ws; ws += (size_t)DM * DI / 2;
  unsigned short* ybuf = (unsigned short*)ws; ws += (size_t)ML * DI / 2;

  const int n0 = ML * DM / 4, n1 = 2 * DI * DM / 4, n2 = DM * DI / 4;
  cvt3_k<<<(n0 + n1 + n2 + 255) / 256, 256, 0, stream>>>(x, xb, n0, in_proj, wb1, n1,
                                                         out_proj, wb2, n2);
  gemm_bf16_64<<<dim3(2 * DI / 64, ML / 64), 256, 0, stream>>>(
      (const short*)xb, (const short*)wb1, xz, ML, 2 * DI, DM);
  conv_silu_k<<<ML * DI / 4 / 256, 256, 0, stream>>>(xz, conv_w, conv_b, xc, sz);
  proj_k<<<ML / 4, 512, 0, stream>>>(xc, x_proj_w, dtp, bccf, lamv);
  delta_k<<<dim3(DI / 256, ML / 8), 256, 0, stream>>>(dtp, dt_w, dt_b, xc, lamv, dxbg);
  scan_pass<false><<<dim3(128, NCHUNK - 1), 256, 0, stream>>>(
      dxbg, (const float4*)bccf, sz, A_log, A_imag, D_skip, aggA, aggU, nullptr);
  scan_combine_k<<<NLANES / 256, 256, 0, stream>>>(aggA, aggU);
  scan_pass<true><<<dim3(128, NCHUNK), 256, 0, stream>>>(
      dxbg, (const float4*)bccf, sz, A_log, A_imag, D_skip, aggA, aggU, ybuf);
  gemm_bf16_64<<<dim3(DM / 64, ML / 64), 256, 0, stream>>>(
      (const short*)ybuf, (const short*)wb2, out, ML, DM, DI);
}